// Round 17
// baseline (380.228 us; speedup 1.0000x reference)
//
#include <hip/hip_runtime.h>
#include <hip/hip_bf16.h>

#define TT 1024
#define DM 256
#define BCN 32

typedef __attribute__((ext_vector_type(8))) short short8;
typedef __attribute__((ext_vector_type(4))) short short4v;
typedef __attribute__((ext_vector_type(4))) float f32x4;

__device__ __forceinline__ void wg_barrier_lds() {
  asm volatile("s_waitcnt lgkmcnt(0)\n\ts_barrier" ::: "memory");
}

__device__ __forceinline__ short bf16b(float f) {
  __hip_bfloat16 h = __float2bfloat16(f);
  return *(short*)&h;
}

// Direct global->LDS DMA (no VGPR round trip, tracked by vmcnt).
// LDS dest must be wave-uniform base; HW adds lane*size. gptr is per-lane.
__device__ __forceinline__ void dma16(void* l, const void* g) {
  __builtin_amdgcn_global_load_lds(
      (const __attribute__((address_space(1))) void*)g,
      (__attribute__((address_space(3))) void*)l, 16, 0, 0);
}
__device__ __forceinline__ void dma4(void* l, const void* g) {
  __builtin_amdgcn_global_load_lds(
      (const __attribute__((address_space(1))) void*)g,
      (__attribute__((address_space(3))) void*)l, 4, 0, 0);
}

// ---------------------------------------------------------------------------
// Kernel MP: merged mask bitpack + weight prep (r13/r16 measured body).
// Blocks 0..511: mask bitpack (8 blocks/CU via 8.4 KB LDS).
//   Bit order: p(k_local) = (k_local>>2) + 8*(k_local&3).
// Blocks 512..639: weight prep, 16B-chunk swizzle ch^(row&7).
// ---------------------------------------------------------------------------
__global__ __launch_bounds__(256, 8) void maskprep_kernel(
    const int* __restrict__ mask, unsigned* __restrict__ mbits,
    const float* __restrict__ w_qkv, const float* __restrict__ w_out,
    __hip_bfloat16* __restrict__ Wb, __hip_bfloat16* __restrict__ Wo)
{
  const int tid = threadIdx.x;

  if (blockIdx.x >= 512) {  // ---- weight prep ----
    int idx = (blockIdx.x - 512) * 256 + tid;  // one 16B chunk each
    const float* src;
    __hip_bfloat16* dst;
    if (idx < 24576) { src = w_qkv; dst = Wb; }
    else { idx -= 24576; src = w_out; dst = Wo; }
    const int r = idx >> 5, ch = idx & 31;
    const float4* wv4 = (const float4*)src + (size_t)r * 64 + ch * 2;
    const float4 f0 = wv4[0], f1 = wv4[1];
    short8 pk;
    pk[0] = bf16b(f0.x); pk[1] = bf16b(f0.y);
    pk[2] = bf16b(f0.z); pk[3] = bf16b(f0.w);
    pk[4] = bf16b(f1.x); pk[5] = bf16b(f1.y);
    pk[6] = bf16b(f1.z); pk[7] = bf16b(f1.w);
    *(short8*)&dst[(size_t)r * 256 + ((ch ^ (r & 7)) << 3)] = pk;
    return;
  }

  // ---- mask bitpack ----
  __shared__ unsigned Wlds[64][33];  // 8.4 KB
  const int m = blockIdx.x;
  const int bc = m >> 4, q0 = (m & 15) * 64;
  const int w = tid >> 6, l = tid & 63;
  const int4* base =
      (const int4*)(mask + (size_t)(bc * 1024 + q0 + w * 16) * 1024) + l;
  int4 v[4], n[4];
#pragma unroll
  for (int s = 0; s < 4; ++s) v[s] = base[s * 64];
#pragma unroll 1
  for (int rr = 0; rr < 16; ++rr) {
    if (rr < 15) {
      const int4* nb = base + (rr + 1) * 256;
#pragma unroll
      for (int s = 0; s < 4; ++s) n[s] = nb[s * 64];
    }
    const int ql = w * 16 + rr;
#pragma unroll
    for (int s = 0; s < 4; ++s) {
      const unsigned long long bx = __ballot(v[s].x != 0);
      const unsigned long long by = __ballot(v[s].y != 0);
      const unsigned long long bz = __ballot(v[s].z != 0);
      const unsigned long long bw = __ballot(v[s].w != 0);
      if (l < 8) {
        const unsigned word =
            (unsigned)((bx >> (8 * l)) & 0xFF) |
            ((unsigned)((by >> (8 * l)) & 0xFF) << 8) |
            ((unsigned)((bz >> (8 * l)) & 0xFF) << 16) |
            ((unsigned)((bw >> (8 * l)) & 0xFF) << 24);
        Wlds[ql][s * 8 + l] = word;
      }
    }
#pragma unroll
    for (int s = 0; s < 4; ++s) v[s] = n[s];
  }
  __syncthreads();
  unsigned* mb = mbits + (size_t)bc * 32 * 1024 + q0;
#pragma unroll
  for (int i = 0; i < 8; ++i) {
    const int idx = tid + i * 256, j = idx >> 6, ql = idx & 63;
    mb[(size_t)j * 1024 + ql] = Wlds[ql][j];
  }
}

// ---------------------------------------------------------------------------
// Kernel 1: QKV projection GEMM (r13/r16 measured-best body, unchanged).
// ---------------------------------------------------------------------------
__global__ __launch_bounds__(256, 2) void qkv_kernel(
    const float* __restrict__ x, const __hip_bfloat16* __restrict__ Wb,
    const float* __restrict__ b_qkv,
    __hip_bfloat16* __restrict__ Qb, __hip_bfloat16* __restrict__ Kb,
    __hip_bfloat16* __restrict__ Vtb)
{
  const int tid = threadIdx.x;
  __shared__ __attribute__((aligned(16))) __hip_bfloat16 Xs[64][264];
  __shared__ __attribute__((aligned(16))) __hip_bfloat16 Wd[2][32 * 256];
  __shared__ __attribute__((aligned(16))) float bls[768];

  const int tt = blockIdx.x & 15, bc = blockIdx.x >> 4;
  const int t0 = tt * 64;
  const int w = tid >> 6, l = tid & 63, quad = l >> 4, lm = l & 15;
  const int lm7 = lm & 7;

  const char* Wg = (const char*)Wb;  // [768][256] bf16 pre-swizzled, 16KB/tile
  auto wissue = [&](int it, int buf) {
    const char* g = Wg + (size_t)it * 16384 + w * 4096 + l * 16;
    char* d = (char*)&Wd[buf][0] + w * 4096;
#pragma unroll
    for (int i = 0; i < 4; ++i) dma16(d + i * 1024, g + i * 1024);
  };

  wissue(0, 0);
  wissue(1, 1);

  if (tid < 192) {
    const float4 bv = *(const float4*)(b_qkv + tid * 4);
    *(float4*)&bls[tid * 4] = bv;
  }

  // transpose-stage Xs[t][d] = x[d][t0+t]: 4x4 register transpose, b64 writes
  {
    const float* xbc = x + (size_t)bc * DM * TT;
    const int t4 = (tid & 15) * 4;
    for (int s = 0; s < 4; ++s) {
      const int d4 = (tid >> 4) * 4 + s * 64;
      f32x4 f[4];
#pragma unroll
      for (int r = 0; r < 4; ++r)
        f[r] = *(const f32x4*)(xbc + (size_t)(d4 + r) * TT + t0 + t4);
#pragma unroll
      for (int r = 0; r < 4; ++r) {
        short4v pk;
#pragma unroll
        for (int c = 0; c < 4; ++c) pk[c] = bf16b(f[c][r]);
        *(short4v*)&Xs[t4 + r][d4] = pk;
      }
    }
  }

#pragma unroll 1
  for (int it = 0; it < 24; ++it) {
    const int buf = it & 1;
    if (it == 0)
      asm volatile("s_waitcnt vmcnt(4)" ::: "memory");
    else if (it < 23)
      asm volatile("s_waitcnt vmcnt(6)" ::: "memory");
    else
      asm volatile("s_waitcnt vmcnt(2)" ::: "memory");
    wg_barrier_lds();

    const int e0 = it * 32;
    const bool vmode = (it >= 16);
    const __hip_bfloat16* WT = &Wd[buf][0];
    f32x4 acc[2] = {};
#pragma unroll
    for (int ks = 0; ks < 8; ++ks) {
      const int k = ks * 32 + quad * 8;
      const short8 xa = *(const short8*)&Xs[w * 16 + lm][k];
      const int c = ((ks * 4 + quad) ^ lm7) << 3;  // de-swizzle
#pragma unroll
      for (int nt = 0; nt < 2; ++nt) {
        const short8 wb2 = *(const short8*)&WT[(nt * 16 + lm) * 256 + c];
        acc[nt] = vmode
            ? __builtin_amdgcn_mfma_f32_16x16x32_bf16(xa, wb2, acc[nt], 0, 0, 0)
            : __builtin_amdgcn_mfma_f32_16x16x32_bf16(wb2, xa, acc[nt], 0, 0, 0);
      }
    }

    if (it < 8) {
      const int t = t0 + w * 16 + lm;
#pragma unroll
      for (int nt = 0; nt < 2; ++nt) {
        const int ebase = e0 + nt * 16 + quad * 4;  // 0..255
        const f32x4 bb = *(const f32x4*)&bls[ebase];
        short4v pk;
#pragma unroll
        for (int r = 0; r < 4; ++r) pk[r] = bf16b(acc[nt][r] + bb[r]);
        *(short4v*)&Qb[((size_t)bc * TT + t) * DM + ebase] = pk;
      }
    } else if (!vmode) {
      const int t = t0 + w * 16 + lm;
#pragma unroll
      for (int nt = 0; nt < 2; ++nt) {
        const int eg = e0 + nt * 16 + quad * 4;   // 256..511
        const int eK = eg - 256;                  // 0..255
        const f32x4 bb = *(const f32x4*)&bls[eg];
        short4v pk;
#pragma unroll
        for (int r = 0; r < 4; ++r) pk[r] = bf16b(acc[nt][r] + bb[r]);
        const int ch = eK >> 3;
        const int off = (((ch ^ (t & 7)) << 3) | (eK & 7));
        *(short4v*)&Kb[((size_t)bc * TT + t) * DM + off] = pk;
      }
    } else {
      const int tb = w * 16 + quad * 4;           // 0..60, mult of 4
      const int kb = tt * 2 + (tb >> 5), tloc = tb & 31;
#pragma unroll
      for (int nt = 0; nt < 2; ++nt) {
        const int e = (e0 - 512) + nt * 16 + lm;  // 0..255
        const float bq = bls[512 + e];
        short4v pk;
#pragma unroll
        for (int r = 0; r < 4; ++r) pk[r] = bf16b(acc[nt][r] + bq);
        *(short4v*)&Vtb[(((size_t)bc * 32 + kb) * 256 + e) * 32 + tloc] = pk;
      }
    }

    wg_barrier_lds();
    if (it < 22) wissue(it + 2, buf);
  }
}

// ---------------------------------------------------------------------------
// Kernel 2: FUSED flash attention + output projection, QBLK=128 (barrier
// amortization: 2x q-rows per block => 2x MFMA work per barrier, half the
// blocks (256), half the total barrier-waits per q-element, half the K/V
// L2 re-read). Mask DMA: 2 x dma4/tile => vmcnt 9->10 counted.
// LDS 77824 B -> 2 blocks/CU:
//   loop: Ks@0(32K) Vs@32K(32K) Ps[128][40]@64K(10240) Msb[2][128]@75776(1K)
//         bout@76800(1K)
//   proj overlay (two 64-row passes): Os[64][264]@0(33792) Wo[2]@33792(32K)
// Per-wave state: qf[2][8], Oa[32], Ol[2] (~230 VGPR, under the 256 cap).
// ---------------------------------------------------------------------------
__global__ __launch_bounds__(256, 2) void attn_kernel(
    const __hip_bfloat16* __restrict__ Qb, const __hip_bfloat16* __restrict__ Kb,
    const __hip_bfloat16* __restrict__ Vtb, const unsigned* __restrict__ Mbits,
    const __hip_bfloat16* __restrict__ Wob, const float* __restrict__ b_out,
    float* __restrict__ out)
{
  const int fid = blockIdx.x;               // 0..255
  const int xcd = fid & 7, slot = fid >> 3; // XCD swizzle: 4 bc per XCD
  const int bc = xcd * 4 + (slot >> 3);
  const int qt = slot & 7;
  const int q0 = qt * 128;

  __shared__ __attribute__((aligned(16))) char smem[77824];
  __hip_bfloat16* Ks = (__hip_bfloat16*)smem;               // [2][32*256]
  __hip_bfloat16* Vs = (__hip_bfloat16*)(smem + 32768);     // [2][256*32]
  __hip_bfloat16 (*Ps)[40] = (__hip_bfloat16(*)[40])(smem + 65536); // [128][40]
  unsigned* Msb = (unsigned*)(smem + 75776);                // [2][128]
  float* bout = (float*)(smem + 76800);                     // [256]
  __hip_bfloat16 (*Os)[264] = (__hip_bfloat16(*)[264])smem; // proj phase
  __hip_bfloat16* Wo = (__hip_bfloat16*)(smem + 33792);     // [2][32*256]

  const int tid = threadIdx.x, w = tid >> 6, l = tid & 63;
  const int quad = l >> 4, lm = l & 15, lm7 = lm & 7;
  const int trow = w * 16 + lm;             // 0..63 within each q-half

  // b_out -> LDS (wave 0 only; visible after first wg_barrier_lds)
  if (tid < 64) {
    const f32x4 bv = *(const f32x4*)(b_out + tid * 4);
    *(f32x4*)&bout[tid * 4] = bv;
  }

  // Q fragments for both q-halves (unswizzled)
  short8 qf[2][8];
#pragma unroll
  for (int h = 0; h < 2; ++h) {
    const __hip_bfloat16* Qg =
        Qb + ((size_t)bc * TT + q0 + h * 64 + trow) * DM + quad * 8;
#pragma unroll
    for (int ks = 0; ks < 8; ++ks) qf[h][ks] = *(const short8*)(Qg + ks * 32);
  }

  const char* KgT = (const char*)(Kb + (size_t)bc * TT * DM);   // +j*16384
  const char* VgT = (const char*)(Vtb + (size_t)bc * TT * DM);  // +j*16384
  const unsigned* MgT = Mbits + ((size_t)bc * 32) * 1024 + q0;  // +j*1024

  short8 ones;
#pragma unroll
  for (int i = 0; i < 8; ++i) ones[i] = (short)0x3F80;  // bf16 1.0

  f32x4 Oa[32] = {};
  f32x4 Ol[2] = {};

  auto issue = [&](int j, int buf) {
    const char* kg = KgT + (size_t)j * 16384 + w * 4096 + l * 16;
    const char* vg = VgT + (size_t)j * 16384 + w * 4096 + l * 16;
    char* kl = (char*)Ks + buf * 16384 + w * 4096;
    char* vl = (char*)Vs + buf * 16384 + w * 4096;
#pragma unroll
    for (int i = 0; i < 4; ++i) dma16(kl + i * 1024, kg + i * 1024);
#pragma unroll
    for (int i = 0; i < 4; ++i) dma16(vl + i * 1024, vg + i * 1024);
    // 128 mask words/tile: 2 x dma4, all waves issue (vmcnt uniform: 10/tile)
    dma4((char*)Msb + buf * 512, MgT + (size_t)j * 1024 + l);
    dma4((char*)Msb + buf * 512 + 256, MgT + (size_t)j * 1024 + 64 + l);
  };

  auto compute = [&](int buf) {
    const __hip_bfloat16* KT = Ks + buf * 8192;
    const __hip_bfloat16* VT = Vs + buf * 8192;
    f32x4 Sa[2][2] = {};  // [kv-half nt][q-half h]
#pragma unroll
    for (int ks = 0; ks < 8; ++ks) {
      const int c = ((ks * 4 + quad) ^ lm7) << 3;  // de-swizzle
      const short8 a0 = *(const short8*)&KT[lm * 256 + c];
      const short8 a1 = *(const short8*)&KT[(lm + 16) * 256 + c];
      Sa[0][0] = __builtin_amdgcn_mfma_f32_16x16x32_bf16(a0, qf[0][ks], Sa[0][0], 0, 0, 0);
      Sa[1][0] = __builtin_amdgcn_mfma_f32_16x16x32_bf16(a1, qf[0][ks], Sa[1][0], 0, 0, 0);
      Sa[0][1] = __builtin_amdgcn_mfma_f32_16x16x32_bf16(a0, qf[1][ks], Sa[0][1], 0, 0, 0);
      Sa[1][1] = __builtin_amdgcn_mfma_f32_16x16x32_bf16(a1, qf[1][ks], Sa[1][1], 0, 0, 0);
    }
#pragma unroll
    for (int h = 0; h < 2; ++h) {
      const unsigned mw = Msb[buf * 128 + h * 64 + trow];
#pragma unroll
      for (int nt = 0; nt < 2; ++nt) {
        short4v pk;
#pragma unroll
        for (int r = 0; r < 4; ++r) {
          // ballot-permuted bit: k_local = nt*16+quad*4+r -> p = nt*4+quad+8*r
          const float p = ((mw >> (nt * 4 + quad + 8 * r)) & 1u)
                              ? 0.f
                              : __expf(fmaf(Sa[nt][h][r], 0.0625f, -8.0f));
          pk[r] = bf16b(p);
        }
        *(short4v*)&Ps[h * 64 + trow][nt * 16 + quad * 4] = pk;
      }
    }
#pragma unroll
    for (int h = 0; h < 2; ++h) {
      const short8 pf = *(const short8*)&Ps[h * 64 + trow][quad * 8];
#pragma unroll
      for (int ct = 0; ct < 16; ++ct) {
        const short8 a = *(const short8*)&VT[(ct * 16 + lm) * 32 + quad * 8];
        Oa[h * 16 + ct] =
            __builtin_amdgcn_mfma_f32_16x16x32_bf16(a, pf, Oa[h * 16 + ct], 0, 0, 0);
      }
      Ol[h] = __builtin_amdgcn_mfma_f32_16x16x32_bf16(ones, pf, Ol[h], 0, 0, 0);
    }
  };

  issue(0, 0);
  issue(1, 1);
#pragma unroll 1
  for (int j = 0; j < 32; ++j) {
    const int buf = j & 1;
    if (j < 31)
      asm volatile("s_waitcnt vmcnt(10)" ::: "memory");  // tile j done; j+1 in flight
    else
      asm volatile("s_waitcnt vmcnt(0)" ::: "memory");
    asm volatile("s_barrier" ::: "memory");
    compute(buf);
    wg_barrier_lds();  // all waves done reading buf (lgkm only)
    if (j < 30) issue(j + 2, buf);
  }

  // ---- Phase B: fused output projection, two 64-row passes ----
  const char* WoG = (const char*)Wob;
  auto pissue = [&](int it, int buf) {
    const char* g = WoG + (size_t)it * 16384 + w * 4096 + l * 16;
    char* d = (char*)Wo + buf * 16384 + w * 4096;
#pragma unroll
    for (int i = 0; i < 4; ++i) dma16(d + i * 1024, g + i * 1024);
  };

#pragma unroll
  for (int h = 0; h < 2; ++h) {
    // Wo prefetch: Vs (h=0) / prior-pass Wo (h=1) dead after preceding barrier
    pissue(0, 0);
    pissue(1, 1);

    const float inv = 1.0f / Ol[h][0];
#pragma unroll
    for (int ct = 0; ct < 16; ++ct) {
      short4v pk;
#pragma unroll
      for (int r = 0; r < 4; ++r) pk[r] = bf16b(Oa[h * 16 + ct][r] * inv);
      *(short4v*)&Os[trow][ct * 16 + quad * 4] = pk;
    }
    wg_barrier_lds();

    short8 osr[8];
#pragma unroll
    for (int ks = 0; ks < 8; ++ks)
      osr[ks] = *(const short8*)&Os[trow][ks * 32 + quad * 8];

    float* outp = out + ((size_t)bc * TT + q0 + h * 64 + trow) * DM;
#pragma unroll 1
    for (int it = 0; it < 8; ++it) {
      const int buf = it & 1;
      if (it == 0)
        asm volatile("s_waitcnt vmcnt(4)" ::: "memory");
      else if (it < 7)
        asm volatile("s_waitcnt vmcnt(6)" ::: "memory");
      else
        asm volatile("s_waitcnt vmcnt(2)" ::: "memory");
      wg_barrier_lds();

      f32x4 acc[2] = {};
#pragma unroll
      for (int ks = 0; ks < 8; ++ks) {
        const int c = ((ks * 4 + quad) ^ lm7) << 3;  // de-swizzle
#pragma unroll
        for (int nt = 0; nt < 2; ++nt) {
          const short8 wa =
              *(const short8*)&Wo[buf * 8192 + (nt * 16 + lm) * 256 + c];
          acc[nt] =
              __builtin_amdgcn_mfma_f32_16x16x32_bf16(wa, osr[ks], acc[nt], 0, 0, 0);
        }
      }
#pragma unroll
      for (int nt = 0; nt < 2; ++nt) {
        const int fb = it * 32 + nt * 16 + quad * 4;
        const f32x4 bb = *(const f32x4*)&bout[fb];
        float4 o;
        o.x = acc[nt][0] + bb[0];
        o.y = acc[nt][1] + bb[1];
        o.z = acc[nt][2] + bb[2];
        o.w = acc[nt][3] + bb[3];
        *(float4*)&outp[fb] = o;
      }

      wg_barrier_lds();  // all waves done reading Wo[buf]
      if (it < 6) pissue(it + 2, buf);
    }
  }
}

// ---------------------------------------------------------------------------
extern "C" void kernel_launch(void* const* d_in, const int* in_sizes, int n_in,
                              void* d_out, int out_size, void* d_ws, size_t ws_size,
                              hipStream_t stream) {
  const float* x = (const float*)d_in[0];
  const int* mask = (const int*)d_in[1];
  const float* w_qkv = (const float*)d_in[2];
  const float* b_qkv = (const float*)d_in[3];
  const float* w_out = (const float*)d_in[4];
  const float* b_out = (const float*)d_in[5];
  float* out = (float*)d_out;

  const size_t N = (size_t)BCN * TT * DM;
  __hip_bfloat16* Qb  = (__hip_bfloat16*)d_ws;   // 16.8 MB
  __hip_bfloat16* Kb  = Qb + N;                  // 16.8 MB, swizzled rows
  __hip_bfloat16* Vtb = Kb + N;                  // 16.8 MB, 16 KB tiles
  unsigned* Mbits     = (unsigned*)(Vtb + N);    // 4 MB, [bc][j][q]
  __hip_bfloat16* Wbp = (__hip_bfloat16*)(Mbits + (size_t)BCN * 32 * 1024); // 0.4 MB
  __hip_bfloat16* Wob = Wbp + 768 * 256;         // 0.13 MB

  maskprep_kernel<<<dim3(640), dim3(256), 0, stream>>>(mask, Mbits,
                                                       w_qkv, w_out, Wbp, Wob);
  qkv_kernel<<<dim3(512), dim3(256), 0, stream>>>(x, Wbp, b_qkv, Qb, Kb, Vtb);
  attn_kernel<<<dim3(256), dim3(256), 0, stream>>>(Qb, Kb, Vtb, Mbits,
                                                   Wob, b_out, out);
}

// Round 18
// 322.067 us; speedup vs baseline: 1.1806x; 1.1806x over previous
//
#include <hip/hip_runtime.h>
#include <hip/hip_bf16.h>

#define TT 1024
#define DM 256
#define BCN 32

typedef __attribute__((ext_vector_type(8))) short short8;
typedef __attribute__((ext_vector_type(4))) short short4v;
typedef __attribute__((ext_vector_type(4))) float f32x4;

__device__ __forceinline__ void wg_barrier_lds() {
  asm volatile("s_waitcnt lgkmcnt(0)\n\ts_barrier" ::: "memory");
}

__device__ __forceinline__ short bf16b(float f) {
  __hip_bfloat16 h = __float2bfloat16(f);
  return *(short*)&h;
}

// Direct global->LDS DMA (no VGPR round trip, tracked by vmcnt).
// LDS dest must be wave-uniform base; HW adds lane*size. gptr is per-lane.
__device__ __forceinline__ void dma16(void* l, const void* g) {
  __builtin_amdgcn_global_load_lds(
      (const __attribute__((address_space(1))) void*)g,
      (__attribute__((address_space(3))) void*)l, 16, 0, 0);
}
__device__ __forceinline__ void dma4(void* l, const void* g) {
  __builtin_amdgcn_global_load_lds(
      (const __attribute__((address_space(1))) void*)g,
      (__attribute__((address_space(3))) void*)l, 4, 0, 0);
}

// ---------------------------------------------------------------------------
// Kernel MP: merged mask bitpack + weight prep (r13/r16 measured body).
// Blocks 0..511: mask bitpack (8 blocks/CU via 8.4 KB LDS).
//   Bit order: p(k_local) = (k_local>>2) + 8*(k_local&3).
// Blocks 512..639: weight prep, 16B-chunk swizzle ch^(row&7).
// ---------------------------------------------------------------------------
__global__ __launch_bounds__(256, 8) void maskprep_kernel(
    const int* __restrict__ mask, unsigned* __restrict__ mbits,
    const float* __restrict__ w_qkv, const float* __restrict__ w_out,
    __hip_bfloat16* __restrict__ Wb, __hip_bfloat16* __restrict__ Wo)
{
  const int tid = threadIdx.x;

  if (blockIdx.x >= 512) {  // ---- weight prep ----
    int idx = (blockIdx.x - 512) * 256 + tid;  // one 16B chunk each
    const float* src;
    __hip_bfloat16* dst;
    if (idx < 24576) { src = w_qkv; dst = Wb; }
    else { idx -= 24576; src = w_out; dst = Wo; }
    const int r = idx >> 5, ch = idx & 31;
    const float4* wv4 = (const float4*)src + (size_t)r * 64 + ch * 2;
    const float4 f0 = wv4[0], f1 = wv4[1];
    short8 pk;
    pk[0] = bf16b(f0.x); pk[1] = bf16b(f0.y);
    pk[2] = bf16b(f0.z); pk[3] = bf16b(f0.w);
    pk[4] = bf16b(f1.x); pk[5] = bf16b(f1.y);
    pk[6] = bf16b(f1.z); pk[7] = bf16b(f1.w);
    *(short8*)&dst[(size_t)r * 256 + ((ch ^ (r & 7)) << 3)] = pk;
    return;
  }

  // ---- mask bitpack ----
  __shared__ unsigned Wlds[64][33];  // 8.4 KB
  const int m = blockIdx.x;
  const int bc = m >> 4, q0 = (m & 15) * 64;
  const int w = tid >> 6, l = tid & 63;
  const int4* base =
      (const int4*)(mask + (size_t)(bc * 1024 + q0 + w * 16) * 1024) + l;
  int4 v[4], n[4];
#pragma unroll
  for (int s = 0; s < 4; ++s) v[s] = base[s * 64];
#pragma unroll 1
  for (int rr = 0; rr < 16; ++rr) {
    if (rr < 15) {
      const int4* nb = base + (rr + 1) * 256;
#pragma unroll
      for (int s = 0; s < 4; ++s) n[s] = nb[s * 64];
    }
    const int ql = w * 16 + rr;
#pragma unroll
    for (int s = 0; s < 4; ++s) {
      const unsigned long long bx = __ballot(v[s].x != 0);
      const unsigned long long by = __ballot(v[s].y != 0);
      const unsigned long long bz = __ballot(v[s].z != 0);
      const unsigned long long bw = __ballot(v[s].w != 0);
      if (l < 8) {
        const unsigned word =
            (unsigned)((bx >> (8 * l)) & 0xFF) |
            ((unsigned)((by >> (8 * l)) & 0xFF) << 8) |
            ((unsigned)((bz >> (8 * l)) & 0xFF) << 16) |
            ((unsigned)((bw >> (8 * l)) & 0xFF) << 24);
        Wlds[ql][s * 8 + l] = word;
      }
    }
#pragma unroll
    for (int s = 0; s < 4; ++s) v[s] = n[s];
  }
  __syncthreads();
  unsigned* mb = mbits + (size_t)bc * 32 * 1024 + q0;
#pragma unroll
  for (int i = 0; i < 8; ++i) {
    const int idx = tid + i * 256, j = idx >> 6, ql = idx & 63;
    mb[(size_t)j * 1024 + ql] = Wlds[ql][j];
  }
}

// ---------------------------------------------------------------------------
// Kernel 1: QKV projection GEMM (r13/r16 measured-best body, unchanged).
// ---------------------------------------------------------------------------
__global__ __launch_bounds__(256, 2) void qkv_kernel(
    const float* __restrict__ x, const __hip_bfloat16* __restrict__ Wb,
    const float* __restrict__ b_qkv,
    __hip_bfloat16* __restrict__ Qb, __hip_bfloat16* __restrict__ Kb,
    __hip_bfloat16* __restrict__ Vtb)
{
  const int tid = threadIdx.x;
  __shared__ __attribute__((aligned(16))) __hip_bfloat16 Xs[64][264];
  __shared__ __attribute__((aligned(16))) __hip_bfloat16 Wd[2][32 * 256];
  __shared__ __attribute__((aligned(16))) float bls[768];

  const int tt = blockIdx.x & 15, bc = blockIdx.x >> 4;
  const int t0 = tt * 64;
  const int w = tid >> 6, l = tid & 63, quad = l >> 4, lm = l & 15;
  const int lm7 = lm & 7;

  const char* Wg = (const char*)Wb;  // [768][256] bf16 pre-swizzled, 16KB/tile
  auto wissue = [&](int it, int buf) {
    const char* g = Wg + (size_t)it * 16384 + w * 4096 + l * 16;
    char* d = (char*)&Wd[buf][0] + w * 4096;
#pragma unroll
    for (int i = 0; i < 4; ++i) dma16(d + i * 1024, g + i * 1024);
  };

  wissue(0, 0);  // DMA tiles 0,1 first: x-staging overlaps their latency
  wissue(1, 1);

  if (tid < 192) {  // bias -> LDS (keeps loop vmem = stores+DMA only)
    const float4 bv = *(const float4*)(b_qkv + tid * 4);
    *(float4*)&bls[tid * 4] = bv;
  }

  // transpose-stage Xs[t][d] = x[d][t0+t]: 4x4 register transpose, b64 writes
  {
    const float* xbc = x + (size_t)bc * DM * TT;
    const int t4 = (tid & 15) * 4;
    for (int s = 0; s < 4; ++s) {
      const int d4 = (tid >> 4) * 4 + s * 64;
      f32x4 f[4];
#pragma unroll
      for (int r = 0; r < 4; ++r)
        f[r] = *(const f32x4*)(xbc + (size_t)(d4 + r) * TT + t0 + t4);
#pragma unroll
      for (int r = 0; r < 4; ++r) {
        short4v pk;
#pragma unroll
        for (int c = 0; c < 4; ++c) pk[c] = bf16b(f[c][r]);
        *(short4v*)&Xs[t4 + r][d4] = pk;
      }
    }
  }

#pragma unroll 1
  for (int it = 0; it < 24; ++it) {
    const int buf = it & 1;
    if (it == 0)
      asm volatile("s_waitcnt vmcnt(4)" ::: "memory");
    else if (it < 23)
      asm volatile("s_waitcnt vmcnt(6)" ::: "memory");
    else
      asm volatile("s_waitcnt vmcnt(2)" ::: "memory");
    wg_barrier_lds();  // all waves' DMA/Xs/bias visible

    const int e0 = it * 32;
    const bool vmode = (it >= 16);
    const __hip_bfloat16* WT = &Wd[buf][0];
    f32x4 acc[2] = {};
#pragma unroll
    for (int ks = 0; ks < 8; ++ks) {
      const int k = ks * 32 + quad * 8;
      const short8 xa = *(const short8*)&Xs[w * 16 + lm][k];
      const int c = ((ks * 4 + quad) ^ lm7) << 3;  // de-swizzle
#pragma unroll
      for (int nt = 0; nt < 2; ++nt) {
        const short8 wb2 = *(const short8*)&WT[(nt * 16 + lm) * 256 + c];
        acc[nt] = vmode
            ? __builtin_amdgcn_mfma_f32_16x16x32_bf16(xa, wb2, acc[nt], 0, 0, 0)
            : __builtin_amdgcn_mfma_f32_16x16x32_bf16(wb2, xa, acc[nt], 0, 0, 0);
      }
    }

    if (it < 8) {
      const int t = t0 + w * 16 + lm;
#pragma unroll
      for (int nt = 0; nt < 2; ++nt) {
        const int ebase = e0 + nt * 16 + quad * 4;  // 0..255
        const f32x4 bb = *(const f32x4*)&bls[ebase];
        short4v pk;
#pragma unroll
        for (int r = 0; r < 4; ++r) pk[r] = bf16b(acc[nt][r] + bb[r]);
        *(short4v*)&Qb[((size_t)bc * TT + t) * DM + ebase] = pk;
      }
    } else if (!vmode) {
      const int t = t0 + w * 16 + lm;
#pragma unroll
      for (int nt = 0; nt < 2; ++nt) {
        const int eg = e0 + nt * 16 + quad * 4;   // 256..511
        const int eK = eg - 256;                  // 0..255
        const f32x4 bb = *(const f32x4*)&bls[eg];
        short4v pk;
#pragma unroll
        for (int r = 0; r < 4; ++r) pk[r] = bf16b(acc[nt][r] + bb[r]);
        const int ch = eK >> 3;
        const int off = (((ch ^ (t & 7)) << 3) | (eK & 7));
        *(short4v*)&Kb[((size_t)bc * TT + t) * DM + off] = pk;
      }
    } else {
      const int tb = w * 16 + quad * 4;           // 0..60, mult of 4
      const int kb = tt * 2 + (tb >> 5), tloc = tb & 31;
#pragma unroll
      for (int nt = 0; nt < 2; ++nt) {
        const int e = (e0 - 512) + nt * 16 + lm;  // 0..255
        const float bq = bls[512 + e];
        short4v pk;
#pragma unroll
        for (int r = 0; r < 4; ++r) pk[r] = bf16b(acc[nt][r] + bq);
        *(short4v*)&Vtb[(((size_t)bc * 32 + kb) * 256 + e) * 32 + tloc] = pk;
      }
    }

    wg_barrier_lds();  // all waves done reading Wd[buf]
    if (it < 22) wissue(it + 2, buf);
  }
}

// ---------------------------------------------------------------------------
// Kernel 2: FUSED flash attention + output projection — REVERTED to the r16
// measured-best body (QBLK=64, 512 blocks, 2 blocks/CU, vmcnt(9), Wo-hoist).
// r17's QBLK=128 regressed (141us): grid 256 = 1 block/CU killed the
// cross-block TLP overlap (OccupancyPercent 11.4 = 4 waves/CU) even though
// work-per-barrier doubled and K/V L2 reuse improved (FETCH 34MB).
// ---------------------------------------------------------------------------
__global__ __launch_bounds__(256, 2) void attn_kernel(
    const __hip_bfloat16* __restrict__ Qb, const __hip_bfloat16* __restrict__ Kb,
    const __hip_bfloat16* __restrict__ Vtb, const unsigned* __restrict__ Mbits,
    const __hip_bfloat16* __restrict__ Wob, const float* __restrict__ b_out,
    float* __restrict__ out)
{
  const int fid = blockIdx.x;
  const int xcd = fid & 7, slot = fid >> 3;
  const int bc = xcd * 4 + (slot >> 4);
  const int qt = slot & 15;
  const int q0 = qt * 64;

  __shared__ __attribute__((aligned(16))) char smem[72192];
  __hip_bfloat16* Ks = (__hip_bfloat16*)smem;               // [2][32*256]
  __hip_bfloat16* Vs = (__hip_bfloat16*)(smem + 32768);     // [2][256*32]
  __hip_bfloat16 (*Ps)[40] = (__hip_bfloat16(*)[40])(smem + 65536);
  unsigned* Msb = (unsigned*)(smem + 70656);                // [2][64]
  float* bout = (float*)(smem + 71168);                     // [256]
  __hip_bfloat16 (*Os)[264] = (__hip_bfloat16(*)[264])smem; // proj phase
  __hip_bfloat16* Wo = (__hip_bfloat16*)(smem + 33792);     // [2][32*256]

  const int tid = threadIdx.x, w = tid >> 6, l = tid & 63;
  const int quad = l >> 4, lm = l & 15, lm7 = lm & 7;
  const int trow = w * 16 + lm;

  // b_out -> LDS (wave 0 only; visible after first wg_barrier_lds)
  if (tid < 64) {
    const f32x4 bv = *(const f32x4*)(b_out + tid * 4);
    *(f32x4*)&bout[tid * 4] = bv;
  }

  // Q fragments direct from global (unswizzled)
  const __hip_bfloat16* Qg =
      Qb + ((size_t)bc * TT + q0 + trow) * DM + quad * 8;
  short8 qf[8];
#pragma unroll
  for (int ks = 0; ks < 8; ++ks) qf[ks] = *(const short8*)(Qg + ks * 32);

  const char* KgT = (const char*)(Kb + (size_t)bc * TT * DM);   // +j*16384
  const char* VgT = (const char*)(Vtb + (size_t)bc * TT * DM);  // +j*16384
  const unsigned* MgT = Mbits + ((size_t)bc * 32) * 1024 + q0;  // +j*1024

  short8 ones;
#pragma unroll
  for (int i = 0; i < 8; ++i) ones[i] = (short)0x3F80;  // bf16 1.0

  f32x4 Oa[16] = {};
  f32x4 Ol = {};

  auto issue = [&](int j, int buf) {
    const char* kg = KgT + (size_t)j * 16384 + w * 4096 + l * 16;
    const char* vg = VgT + (size_t)j * 16384 + w * 4096 + l * 16;
    char* kl = (char*)Ks + buf * 16384 + w * 4096;
    char* vl = (char*)Vs + buf * 16384 + w * 4096;
#pragma unroll
    for (int i = 0; i < 4; ++i) dma16(kl + i * 1024, kg + i * 1024);
#pragma unroll
    for (int i = 0; i < 4; ++i) dma16(vl + i * 1024, vg + i * 1024);
    // all waves issue the (identical) mask DMA so vmcnt stays uniform
    dma4((char*)Msb + buf * 256, MgT + (size_t)j * 1024 + l);
  };

  auto compute = [&](int buf) {
    const __hip_bfloat16* KT = Ks + buf * 8192;
    const __hip_bfloat16* VT = Vs + buf * 8192;
    f32x4 Sa0 = {}, Sa1 = {};
#pragma unroll
    for (int ks = 0; ks < 8; ++ks) {
      const int c = ((ks * 4 + quad) ^ lm7) << 3;  // de-swizzle
      const short8 a0 = *(const short8*)&KT[lm * 256 + c];
      const short8 a1 = *(const short8*)&KT[(lm + 16) * 256 + c];
      Sa0 = __builtin_amdgcn_mfma_f32_16x16x32_bf16(a0, qf[ks], Sa0, 0, 0, 0);
      Sa1 = __builtin_amdgcn_mfma_f32_16x16x32_bf16(a1, qf[ks], Sa1, 0, 0, 0);
    }
    const unsigned mw = Msb[buf * 64 + trow];
#pragma unroll
    for (int nt = 0; nt < 2; ++nt) {
      const f32x4 Sa = nt ? Sa1 : Sa0;
      short4v pk;
#pragma unroll
      for (int r = 0; r < 4; ++r) {
        // ballot-permuted bit: k_local = nt*16+quad*4+r -> p = nt*4+quad+8*r
        const float p = ((mw >> (nt * 4 + quad + 8 * r)) & 1u)
                            ? 0.f
                            : __expf(fmaf(Sa[r], 0.0625f, -8.0f));
        pk[r] = bf16b(p);
      }
      *(short4v*)&Ps[trow][nt * 16 + quad * 4] = pk;
    }
    const short8 pf = *(const short8*)&Ps[trow][quad * 8];
#pragma unroll
    for (int ct = 0; ct < 16; ++ct) {
      const short8 a = *(const short8*)&VT[(ct * 16 + lm) * 32 + quad * 8];
      Oa[ct] = __builtin_amdgcn_mfma_f32_16x16x32_bf16(a, pf, Oa[ct], 0, 0, 0);
    }
    Ol = __builtin_amdgcn_mfma_f32_16x16x32_bf16(ones, pf, Ol, 0, 0, 0);
  };

  issue(0, 0);
  issue(1, 1);
#pragma unroll 1
  for (int j = 0; j < 32; ++j) {
    const int buf = j & 1;
    if (j < 31)
      asm volatile("s_waitcnt vmcnt(9)" ::: "memory");  // tile j done; j+1 in flight
    else
      asm volatile("s_waitcnt vmcnt(0)" ::: "memory");
    asm volatile("s_barrier" ::: "memory");
    compute(buf);
    wg_barrier_lds();  // all waves done reading buf (lgkm only)
    if (j < 30) issue(j + 2, buf);
  }

  // ---- Phase B: fused output projection ----
  // Hoisted Wo prefetch: Vs dead block-wide after the j=31 barrier; Wo
  // overlay (33792..66559) does not intersect Os (0..33791).
  const char* WoG = (const char*)Wob;
  auto pissue = [&](int it, int buf) {
    const char* g = WoG + (size_t)it * 16384 + w * 4096 + l * 16;
    char* d = (char*)Wo + buf * 16384 + w * 4096;
#pragma unroll
    for (int i = 0; i < 4; ++i) dma16(d + i * 1024, g + i * 1024);
  };
  pissue(0, 0);
  pissue(1, 1);

  const float inv = 1.0f / Ol[0];
#pragma unroll
  for (int ct = 0; ct < 16; ++ct) {
    short4v pk;
#pragma unroll
    for (int r = 0; r < 4; ++r) pk[r] = bf16b(Oa[ct][r] * inv);
    *(short4v*)&Os[trow][ct * 16 + quad * 4] = pk;
  }
  wg_barrier_lds();

  short8 osr[8];
#pragma unroll
  for (int ks = 0; ks < 8; ++ks)
    osr[ks] = *(const short8*)&Os[trow][ks * 32 + quad * 8];

  float* outp = out + ((size_t)bc * TT + q0 + trow) * DM;
#pragma unroll 1
  for (int it = 0; it < 8; ++it) {
    const int buf = it & 1;
    if (it == 0)
      asm volatile("s_waitcnt vmcnt(4)" ::: "memory");
    else if (it < 7)
      asm volatile("s_waitcnt vmcnt(6)" ::: "memory");
    else
      asm volatile("s_waitcnt vmcnt(2)" ::: "memory");
    wg_barrier_lds();

    f32x4 acc[2] = {};
#pragma unroll
    for (int ks = 0; ks < 8; ++ks) {
      const int c = ((ks * 4 + quad) ^ lm7) << 3;  // de-swizzle
#pragma unroll
      for (int nt = 0; nt < 2; ++nt) {
        const short8 wa = *(const short8*)&Wo[buf * 8192 + (nt * 16 + lm) * 256 + c];
        acc[nt] = __builtin_amdgcn_mfma_f32_16x16x32_bf16(wa, osr[ks], acc[nt], 0, 0, 0);
      }
    }
#pragma unroll
    for (int nt = 0; nt < 2; ++nt) {
      const int fb = it * 32 + nt * 16 + quad * 4;
      const f32x4 bb = *(const f32x4*)&bout[fb];
      float4 o;
      o.x = acc[nt][0] + bb[0];
      o.y = acc[nt][1] + bb[1];
      o.z = acc[nt][2] + bb[2];
      o.w = acc[nt][3] + bb[3];
      *(float4*)&outp[fb] = o;
    }

    wg_barrier_lds();  // all waves done reading Wo[buf]
    if (it < 6) pissue(it + 2, buf);
  }
}

// ---------------------------------------------------------------------------
extern "C" void kernel_launch(void* const* d_in, const int* in_sizes, int n_in,
                              void* d_out, int out_size, void* d_ws, size_t ws_size,
                              hipStream_t stream) {
  const float* x = (const float*)d_in[0];
  const int* mask = (const int*)d_in[1];
  const float* w_qkv = (const float*)d_in[2];
  const float* b_qkv = (const float*)d_in[3];
  const float* w_out = (const float*)d_in[4];
  const float* b_out = (const float*)d_in[5];
  float* out = (float*)d_out;

  const size_t N = (size_t)BCN * TT * DM;
  __hip_bfloat16* Qb  = (__hip_bfloat16*)d_ws;   // 16.8 MB
  __hip_bfloat16* Kb  = Qb + N;                  // 16.8 MB, swizzled rows
  __hip_bfloat16* Vtb = Kb + N;                  // 16.8 MB, 16 KB tiles
  unsigned* Mbits     = (unsigned*)(Vtb + N);    // 4 MB, [bc][j][q]
  __hip_bfloat16* Wbp = (__hip_bfloat16*)(Mbits + (size_t)BCN * 32 * 1024); // 0.4 MB
  __hip_bfloat16* Wob = Wbp + 768 * 256;         // 0.13 MB

  maskprep_kernel<<<dim3(640), dim3(256), 0, stream>>>(mask, Mbits,
                                                       w_qkv, w_out, Wbp, Wob);
  qkv_kernel<<<dim3(512), dim3(256), 0, stream>>>(x, Wbp, b_qkv, Qb, Kb, Vtb);
  attn_kernel<<<dim3(512), dim3(256), 0, stream>>>(Qb, Kb, Vtb, Mbits,
                                                   Wob, b_out, out);
}